// Round 6
// baseline (567.246 us; speedup 1.0000x reference)
//
#include <hip/hip_runtime.h>

typedef float f32x4 __attribute__((ext_vector_type(4)));
typedef unsigned int u32x4 __attribute__((ext_vector_type(4)));
typedef _Float16 f16x8 __attribute__((ext_vector_type(8)));
typedef unsigned short u16;
typedef unsigned int u32;

// ---- constants ----
#define NWIN 8192
#define MAX_LOG_SCALE 4.605170185988091f  // log(100)

// LDS regions (32 KB total -> 5 blocks/CU):
//   A [0,16K):    X1 -> VT wave-slices (1b, wave-local) -> Q -> O
//   B [16K,32K):  X2 -> K -> P wave-slices (phase 2, after barrier 4)
// Wave-local overlays in A (no barrier): wave wv's X1 strip rows [16wv,16wv+16)
// = bytes [4K*wv,4K*(wv+1)) = its VT slice rows [32wv,32wv+32) (stride 128)
// = its Q strip rows [16wv,16wv+16) (stride 256).
// After barrier (4) all Q/K fragments are in registers -> A and B both dead:
// O overlays A; P strips overlay B (wave-private 4 KB slices).
#define RA 0
#define RB 16384
#define LDS_BYTES 32768

__device__ __forceinline__ void mfma16(f32x4& acc, u32x4 a, u32x4 b) {
  acc = __builtin_amdgcn_mfma_f32_16x16x32_f16(
      __builtin_bit_cast(f16x8, a), __builtin_bit_cast(f16x8, b), acc, 0, 0, 0);
}

__device__ __forceinline__ u16 f2h(float f) {
  return __builtin_bit_cast(u16, (_Float16)f);
}
__device__ __forceinline__ u32 pkh(float x, float y) {  // packed f32->f16 (RTZ)
  return __builtin_bit_cast(u32, __builtin_amdgcn_cvt_pkrtz(x, y));
}

// XOR swizzle within a row (row stride 256B or 128B); bijective, stays in-row.
__device__ __forceinline__ int swz(int row, int colbyte) {
  return colbyte ^ ((row & 7) << 4);
}
__device__ __forceinline__ u32x4 ldsfrag(const char* p, int row, int colbyte, int stride) {
  return *(const u32x4*)(p + row * stride + swz(row, colbyte));
}
__device__ __forceinline__ void lds_st16(char* p, int row, int colbyte, int stride, u16 v) {
  *(u16*)(p + row * stride + swz(row, colbyte)) = v;
}
__device__ __forceinline__ u32x4 gfrag(const u16* p) {
  return *(const u32x4*)p;
}

// ---------- weight prep: f32 -> f16 (contiguous qw|kvw|pw) + head scales ----------
__global__ void wca_prep(const float* __restrict__ qw, const float* __restrict__ kvw,
                         const float* __restrict__ pw, const float* __restrict__ ls,
                         u16* __restrict__ wh, float* __restrict__ scales) {
  int t = blockIdx.x * 256 + threadIdx.x;   // 0..16383, one float4 each
  int e = t * 4;
  const float* src;
  int off;
  if (e < 16384)      { src = qw;  off = e; }
  else if (e < 49152) { src = kvw; off = e - 16384; }
  else                { src = pw;  off = e - 49152; }
  float4 v = *(const float4*)(src + off);
  uint2 o = { pkh(v.x, v.y), pkh(v.z, v.w) };
  *(uint2*)(wh + e) = o;
  if (t < 4) scales[t] = __expf(fminf(ls[t], MAX_LOG_SCALE));
}

// ---------- main kernel: one window per block, 4 waves, 5 blocks/CU ----------
__global__ void __launch_bounds__(256, 5) wca_kernel(
    const float* __restrict__ x1, const float* __restrict__ x2,
    const float* __restrict__ qb, const float* __restrict__ vb,
    const float* __restrict__ pb, const u16* __restrict__ wh,
    const float* __restrict__ scales, float* __restrict__ out) {
  __shared__ char smem[LDS_BYTES];
  const int b = blockIdx.x;
  const int tid = threadIdx.x;
  const int wv = tid >> 6;          // wave 0..3 (= head in phase 2/3)
  const int lane = tid & 63;
  const int lr = lane & 15;         // row/col within 16-tile
  const int lg = lane >> 4;         // k-group / row-group
  const u16* qw  = wh;              // 128x128
  const u16* kvw = wh + 16384;      // 256x128
  const u16* pw  = wh + 49152;      // 128x128

  // ---- phase 0: load x1,x2 -> f16 LDS (all 16 loads hoisted for MLP) ----
  {
    const float4* p1 = (const float4*)(x1 + (size_t)b * 8192);
    const float4* p2 = (const float4*)(x2 + (size_t)b * 8192);
    float4 a[8], c[8];
#pragma unroll
    for (int i = 0; i < 8; ++i) { a[i] = p1[i * 256 + tid]; c[i] = p2[i * 256 + tid]; }
#pragma unroll
    for (int i = 0; i < 8; ++i) {
      int e = (i * 256 + tid) * 4;
      int row = e >> 7;
      int colb = (e & 127) * 2;
      uint2 pa = { pkh(a[i].x, a[i].y), pkh(a[i].z, a[i].w) };
      uint2 pc = { pkh(c[i].x, c[i].y), pkh(c[i].z, c[i].w) };
      *(uint2*)(smem + RA + row * 256 + swz(row, colb)) = pa;
      *(uint2*)(smem + RB + row * 256 + swz(row, colb)) = pc;
    }
  }
  __syncthreads();  // (1) X1,X2 visible

  // ---- phase 1a: own-strip x1/x2 fragments -> registers (wave-local rows) ----
  const int r0 = wv * 16;
  u32x4 ax1[4], ax2[4];
#pragma unroll
  for (int kc = 0; kc < 4; ++kc) {
    ax1[kc] = ldsfrag(smem + RA, r0 + lr, kc * 64 + lg * 16, 256);
    ax2[kc] = ldsfrag(smem + RB, r0 + lr, kc * 64 + lg * 16, 256);
  }
  // NO barrier: wave wv's VT slice (below) = its own X1 strip bytes, self-read above.

  // ---- phase 1b: vT(j,n)=sum_k kvw[128+j][k]*x2[n][k]+vb[j], j in [32wv,32wv+32) ----
  u32x4 bv[2][2];   // PV B-operand, read back wave-locally, held to PV
  {
    u32x4 akv[2][4];
#pragma unroll
    for (int jt = 0; jt < 2; ++jt)
#pragma unroll
      for (int kc = 0; kc < 4; ++kc)
        akv[jt][kc] = gfrag(kvw + (128 + wv * 32 + jt * 16 + lr) * 128 + kc * 32 + lg * 8);
    float vbias[2][4];
#pragma unroll
    for (int jt = 0; jt < 2; ++jt)
#pragma unroll
      for (int i = 0; i < 4; ++i)
        vbias[jt][i] = vb[wv * 32 + jt * 16 + lg * 4 + i];
#pragma unroll
    for (int nt = 0; nt < 4; ++nt) {
      u32x4 bx[4];
#pragma unroll
      for (int kc = 0; kc < 4; ++kc)
        bx[kc] = ldsfrag(smem + RB, nt * 16 + lr, kc * 64 + lg * 16, 256);
      f32x4 acc[2] = {{0.f,0.f,0.f,0.f},{0.f,0.f,0.f,0.f}};
#pragma unroll
      for (int jt = 0; jt < 2; ++jt)
#pragma unroll
        for (int kc = 0; kc < 4; ++kc)
          mfma16(acc[jt], akv[jt][kc], bx[kc]);
#pragma unroll
      for (int jt = 0; jt < 2; ++jt)
#pragma unroll
        for (int i = 0; i < 4; ++i) {
          int row = wv * 32 + jt * 16 + lg * 4 + i;   // bytes in own A slice
          lds_st16(smem + RA, row, (nt * 16 + lr) * 2, 128,
                   f2h(acc[jt][i] + vbias[jt][i]));
        }
    }
    // wave-local readback (compiler inserts lgkmcnt for the RAW dependency)
#pragma unroll
    for (int ct = 0; ct < 2; ++ct)
#pragma unroll
      for (int kc = 0; kc < 2; ++kc)
        bv[ct][kc] = ldsfrag(smem + RA, wv * 32 + ct * 16 + lr, kc * 64 + lg * 16, 128);
  }
  __syncthreads();  // (2) all waves done reading X2 (bx) -> K may overlay B

  // ---- phase 1c: q (x1@qw^T+qb) -> A own strip, k (x2@kvw^T) -> B own strip ----
#pragma unroll
  for (int h = 0; h < 4; ++h) {
#pragma unroll
    for (int which = 0; which < 2; ++which) {
      const u16* W = which ? kvw : qw;
      f32x4 a0 = {0.f, 0.f, 0.f, 0.f}, a1 = {0.f, 0.f, 0.f, 0.f};
#pragma unroll
      for (int kc = 0; kc < 4; ++kc) {
        u32x4 b0 = gfrag(W + (h * 32 + lr) * 128 + kc * 32 + lg * 8);
        u32x4 b1 = gfrag(W + (h * 32 + 16 + lr) * 128 + kc * 32 + lg * 8);
        u32x4 a = which ? ax2[kc] : ax1[kc];
        mfma16(a0, a, b0);
        mfma16(a1, a, b1);
      }
      if (!which) {
        float b0 = qb[h * 32 + lr], b1 = qb[h * 32 + 16 + lr];
#pragma unroll
        for (int i = 0; i < 4; ++i) { a0[i] += b0; a1[i] += b1; }
      }
      float s[4];
#pragma unroll
      for (int i = 0; i < 4; ++i) s[i] = a0[i] * a0[i] + a1[i] * a1[i];
#pragma unroll
      for (int m = 1; m < 16; m <<= 1)
#pragma unroll
        for (int i = 0; i < 4; ++i) s[i] += __shfl_xor(s[i], m, 64);
      char* dst = smem + (which ? RB : RA);
#pragma unroll
      for (int i = 0; i < 4; ++i) {
        float r = 1.0f / fmaxf(sqrtf(s[i]), 1e-12f);
        int row = r0 + lg * 4 + i;
        lds_st16(dst, row, (h * 32 + lr) * 2, 256, f2h(a0[i] * r));
        lds_st16(dst, row, (h * 32 + 16 + lr) * 2, 256, f2h(a1[i] * r));
      }
    }
  }
  __syncthreads();  // (3) Q,K complete

  // ---- phase 2: per-wave head wv, fully wave-local after the operand loads ----
  const float sc = scales[wv];
  u32x4 aq[4], bk[4];
#pragma unroll
  for (int t = 0; t < 4; ++t) {
    aq[t] = ldsfrag(smem + RA, t * 16 + lr, wv * 64 + lg * 16, 256);
    bk[t] = ldsfrag(smem + RB, t * 16 + lr, wv * 64 + lg * 16, 256);
  }
  __syncthreads();  // (4) all Q/K reads done -> A and B both dead:
                    // O may overlay A, P strips may overlay B.

  char* Pbase = smem + RB + wv * 4096;  // wave-private 16x64 f16 strip (2 KB of 4 KB slice)
  f32x4 o[4][2];
#pragma unroll
  for (int nt = 0; nt < 4; ++nt) {
    // QK^T for q-rows [16nt,16nt+16), all 64 k
    f32x4 att[4];
#pragma unroll
    for (int mt = 0; mt < 4; ++mt) {
      f32x4 z = {0.f, 0.f, 0.f, 0.f};
      mfma16(z, aq[nt], bk[mt]);
      att[mt] = z;
    }
    // softmax; logits = sc*cos <= sc -> fixed max bound sc (no max reduce)
    float sum[4] = {0.f, 0.f, 0.f, 0.f};
#pragma unroll
    for (int i = 0; i < 4; ++i)
#pragma unroll
      for (int mt = 0; mt < 4; ++mt) {
        float p = __expf(fmaf(att[mt][i], sc, -sc));
        att[mt][i] = p;
        sum[i] += p;
      }
#pragma unroll
    for (int m = 1; m < 16; m <<= 1)
#pragma unroll
      for (int i = 0; i < 4; ++i) sum[i] += __shfl_xor(sum[i], m, 64);
    // P strip (rows local 0..15) -> wave-private LDS, then PV (wave-local RAW)
#pragma unroll
    for (int i = 0; i < 4; ++i) {
      float rs = 1.0f / sum[i];
      int row = lg * 4 + i;
#pragma unroll
      for (int mt = 0; mt < 4; ++mt)
        lds_st16(Pbase, row, (mt * 16 + lr) * 2, 128, f2h(att[mt][i] * rs));
    }
    u32x4 ap[2];
#pragma unroll
    for (int kc = 0; kc < 2; ++kc)
      ap[kc] = ldsfrag(Pbase, lr, kc * 64 + lg * 16, 128);
#pragma unroll
    for (int ct = 0; ct < 2; ++ct) {
      f32x4 z = {0.f, 0.f, 0.f, 0.f};
#pragma unroll
      for (int kc = 0; kc < 2; ++kc) mfma16(z, ap[kc], bv[ct][kc]);
      o[nt][ct] = z;
    }
  }

  // Hoist phase-3 weight frags (L2) to overlap with O-store + barrier below.
  u32x4 bp[2][4];
#pragma unroll
  for (int ct = 0; ct < 2; ++ct)
#pragma unroll
    for (int kc = 0; kc < 4; ++kc)
      bp[ct][kc] = gfrag(pw + (wv * 32 + ct * 16 + lr) * 128 + kc * 32 + lg * 8);
  float pbv[2] = { pb[wv * 32 + lr], pb[wv * 32 + 16 + lr] };

  // store o (all rows x own head's 32 cols) into A (all aq reads done at barrier 4)
#pragma unroll
  for (int nt = 0; nt < 4; ++nt)
#pragma unroll
    for (int ct = 0; ct < 2; ++ct)
#pragma unroll
      for (int i = 0; i < 4; ++i) {
        int row = nt * 16 + lg * 4 + i;
        lds_st16(smem + RA, row, (wv * 32 + ct * 16 + lr) * 2, 256, f2h(o[nt][ct][i]));
      }
  __syncthreads();  // (5) O complete

  // ---- phase 3 (column-scheme): out[:, 32wv..32wv+32) = O @ pw[own rows]^T + pb ----
  {
    float* ob = out + (size_t)b * 8192;
#pragma unroll
    for (int np = 0; np < 2; ++np) {   // two nt-halves to bound VGPR
      u32x4 af[2][4];
#pragma unroll
      for (int t = 0; t < 2; ++t)
#pragma unroll
        for (int kc = 0; kc < 4; ++kc)
          af[t][kc] = ldsfrag(smem + RA, (np * 2 + t) * 16 + lr, kc * 64 + lg * 16, 256);
#pragma unroll
      for (int t = 0; t < 2; ++t)
#pragma unroll
        for (int ct = 0; ct < 2; ++ct) {
          f32x4 acc = {0.f, 0.f, 0.f, 0.f};
#pragma unroll
          for (int kc = 0; kc < 4; ++kc) mfma16(acc, af[t][kc], bp[ct][kc]);
#pragma unroll
          for (int i = 0; i < 4; ++i) {
            int row = (np * 2 + t) * 16 + lg * 4 + i;
            ob[row * 128 + wv * 32 + ct * 16 + lr] = acc[i] + pbv[ct];
          }
        }
    }
  }
}

extern "C" void kernel_launch(void* const* d_in, const int* in_sizes, int n_in,
                              void* d_out, int out_size, void* d_ws, size_t ws_size,
                              hipStream_t stream) {
  const float* x1 = (const float*)d_in[0];
  const float* x2 = (const float*)d_in[1];
  const float* qw = (const float*)d_in[2];
  const float* qb = (const float*)d_in[3];
  const float* kvw = (const float*)d_in[4];
  const float* vb = (const float*)d_in[5];
  const float* ls = (const float*)d_in[6];
  const float* pw = (const float*)d_in[7];
  const float* pb = (const float*)d_in[8];
  u16* wh = (u16*)d_ws;                           // 65536 f16 = 128 KB
  float* scales = (float*)((char*)d_ws + 131072); // 4 floats

  wca_prep<<<64, 256, 0, stream>>>(qw, kvw, pw, ls, wh, scales);
  wca_kernel<<<NWIN, 256, 0, stream>>>(x1, x2, qb, vb, pb, wh, scales, (float*)d_out);
}

// Round 7
// 413.494 us; speedup vs baseline: 1.3718x; 1.3718x over previous
//
#include <hip/hip_runtime.h>

typedef float f32x4 __attribute__((ext_vector_type(4)));
typedef unsigned int u32x4 __attribute__((ext_vector_type(4)));
typedef _Float16 f16x8 __attribute__((ext_vector_type(8)));
typedef unsigned short u16;
typedef unsigned int u32;

// ---- constants ----
#define NWIN 8192
#define MAX_LOG_SCALE 4.605170185988091f  // log(100)
#define LOG2E 1.4426950408889634f

// LDS regions (32 KB total -> 5 blocks/CU by LDS; launch_bounds kept at 4
// waves/EU so the register allocator has the full 128-reg budget — rounds 4+6
// proved that capping to 5 waves/EU (~96 regs) spills ~1.5 GB of scratch).
//   A [0,16K):    X1 -> VT wave-slices (1b, wave-local) -> Q -> O
//   B [16K,32K):  X2 -> K -> P wave-slices (phase 2, after barrier 4)
// Wave-local overlays in A (no barrier): wave wv's X1 strip rows [16wv,16wv+16)
// = bytes [4K*wv,4K*(wv+1)) = its VT slice rows [32wv,32wv+32) (stride 128)
// = its Q strip rows [16wv,16wv+16) (stride 256).
// After barrier (4) all Q/K fragments are in registers -> A and B both dead:
// O overlays A; P strips overlay B (wave-private 4 KB slices).
#define RA 0
#define RB 16384
#define LDS_BYTES 32768

__device__ __forceinline__ void mfma16(f32x4& acc, u32x4 a, u32x4 b) {
  acc = __builtin_amdgcn_mfma_f32_16x16x32_f16(
      __builtin_bit_cast(f16x8, a), __builtin_bit_cast(f16x8, b), acc, 0, 0, 0);
}

__device__ __forceinline__ u16 f2h(float f) {
  return __builtin_bit_cast(u16, (_Float16)f);
}
__device__ __forceinline__ u32 pkh(float x, float y) {  // packed f32->f16 (RTZ)
  return __builtin_bit_cast(u32, __builtin_amdgcn_cvt_pkrtz(x, y));
}

// XOR swizzle within a row (row stride 256B or 128B); bijective, stays in-row.
__device__ __forceinline__ int swz(int row, int colbyte) {
  return colbyte ^ ((row & 7) << 4);
}
__device__ __forceinline__ u32x4 ldsfrag(const char* p, int row, int colbyte, int stride) {
  return *(const u32x4*)(p + row * stride + swz(row, colbyte));
}
__device__ __forceinline__ void lds_st16(char* p, int row, int colbyte, int stride, u16 v) {
  *(u16*)(p + row * stride + swz(row, colbyte)) = v;
}
__device__ __forceinline__ u32x4 gfrag(const u16* p) {
  return *(const u32x4*)p;
}

// ---------- weight prep: f32 -> f16 (contiguous qw|kvw|pw) + head scales ----------
__global__ void wca_prep(const float* __restrict__ qw, const float* __restrict__ kvw,
                         const float* __restrict__ pw, const float* __restrict__ ls,
                         u16* __restrict__ wh, float* __restrict__ scales) {
  int t = blockIdx.x * 256 + threadIdx.x;   // 0..16383, one float4 each
  int e = t * 4;
  const float* src;
  int off;
  if (e < 16384)      { src = qw;  off = e; }
  else if (e < 49152) { src = kvw; off = e - 16384; }
  else                { src = pw;  off = e - 49152; }
  float4 v = *(const float4*)(src + off);
  uint2 o = { pkh(v.x, v.y), pkh(v.z, v.w) };
  *(uint2*)(wh + e) = o;
  // pre-fold log2(e) so softmax uses exp2 (single v_exp_f32)
  if (t < 4) scales[t] = __expf(fminf(ls[t], MAX_LOG_SCALE)) * LOG2E;
}

// ---------- main kernel: one window per block, 4 waves ----------
__global__ void __launch_bounds__(256, 4) wca_kernel(
    const float* __restrict__ x1, const float* __restrict__ x2,
    const float* __restrict__ qb, const float* __restrict__ vb,
    const float* __restrict__ pb, const u16* __restrict__ wh,
    const float* __restrict__ scales, float* __restrict__ out) {
  __shared__ char smem[LDS_BYTES];
  const int b = blockIdx.x;
  const int tid = threadIdx.x;
  const int wv = tid >> 6;          // wave 0..3 (= head in phase 2/3)
  const int lane = tid & 63;
  const int lr = lane & 15;         // row/col within 16-tile
  const int lg = lane >> 4;         // k-group / row-group
  const u16* qw  = wh;              // 128x128
  const u16* kvw = wh + 16384;      // 256x128
  const u16* pw  = wh + 49152;      // 128x128

  // ---- phase 0: load x1,x2 -> f16 LDS (all 16 loads hoisted for MLP) ----
  {
    const float4* p1 = (const float4*)(x1 + (size_t)b * 8192);
    const float4* p2 = (const float4*)(x2 + (size_t)b * 8192);
    float4 a[8], c[8];
#pragma unroll
    for (int i = 0; i < 8; ++i) { a[i] = p1[i * 256 + tid]; c[i] = p2[i * 256 + tid]; }
#pragma unroll
    for (int i = 0; i < 8; ++i) {
      int e = (i * 256 + tid) * 4;
      int row = e >> 7;
      int colb = (e & 127) * 2;
      uint2 pa = { pkh(a[i].x, a[i].y), pkh(a[i].z, a[i].w) };
      uint2 pc = { pkh(c[i].x, c[i].y), pkh(c[i].z, c[i].w) };
      *(uint2*)(smem + RA + row * 256 + swz(row, colb)) = pa;
      *(uint2*)(smem + RB + row * 256 + swz(row, colb)) = pc;
    }
  }
  __syncthreads();  // (1) X1,X2 visible

  // ---- phase 1a: own-strip x1/x2 fragments -> registers (wave-local rows) ----
  const int r0 = wv * 16;
  u32x4 ax1[4], ax2[4];
#pragma unroll
  for (int kc = 0; kc < 4; ++kc) {
    ax1[kc] = ldsfrag(smem + RA, r0 + lr, kc * 64 + lg * 16, 256);
    ax2[kc] = ldsfrag(smem + RB, r0 + lr, kc * 64 + lg * 16, 256);
  }
  // NO barrier: wave wv's VT slice (below) = its own X1 strip bytes, self-read above.

  // ---- phase 1b: vT(j,n)=sum_k kvw[128+j][k]*x2[n][k]+vb[j], j in [32wv,32wv+32) ----
  u32x4 bv[2][2];   // PV B-operand, read back wave-locally, held to PV
  {
    u32x4 akv[2][4];
#pragma unroll
    for (int jt = 0; jt < 2; ++jt)
#pragma unroll
      for (int kc = 0; kc < 4; ++kc)
        akv[jt][kc] = gfrag(kvw + (128 + wv * 32 + jt * 16 + lr) * 128 + kc * 32 + lg * 8);
    float vbias[2][4];
#pragma unroll
    for (int jt = 0; jt < 2; ++jt)
#pragma unroll
      for (int i = 0; i < 4; ++i)
        vbias[jt][i] = vb[wv * 32 + jt * 16 + lg * 4 + i];
#pragma unroll
    for (int nt = 0; nt < 4; ++nt) {
      u32x4 bx[4];
#pragma unroll
      for (int kc = 0; kc < 4; ++kc)
        bx[kc] = ldsfrag(smem + RB, nt * 16 + lr, kc * 64 + lg * 16, 256);
      f32x4 acc[2] = {{0.f,0.f,0.f,0.f},{0.f,0.f,0.f,0.f}};
#pragma unroll
      for (int jt = 0; jt < 2; ++jt)
#pragma unroll
        for (int kc = 0; kc < 4; ++kc)
          mfma16(acc[jt], akv[jt][kc], bx[kc]);
#pragma unroll
      for (int jt = 0; jt < 2; ++jt)
#pragma unroll
        for (int i = 0; i < 4; ++i) {
          int row = wv * 32 + jt * 16 + lg * 4 + i;   // bytes in own A slice
          lds_st16(smem + RA, row, (nt * 16 + lr) * 2, 128,
                   f2h(acc[jt][i] + vbias[jt][i]));
        }
    }
    // wave-local readback (compiler inserts lgkmcnt for the RAW dependency)
#pragma unroll
    for (int ct = 0; ct < 2; ++ct)
#pragma unroll
      for (int kc = 0; kc < 2; ++kc)
        bv[ct][kc] = ldsfrag(smem + RA, wv * 32 + ct * 16 + lr, kc * 64 + lg * 16, 128);
  }
  __syncthreads();  // (2) all waves done reading X2 (bx) -> K may overlay B

  // ---- phase 1c: q (x1@qw^T+qb) -> A own strip, k (x2@kvw^T) -> B own strip ----
#pragma unroll
  for (int h = 0; h < 4; ++h) {
#pragma unroll
    for (int which = 0; which < 2; ++which) {
      const u16* W = which ? kvw : qw;
      f32x4 a0 = {0.f, 0.f, 0.f, 0.f}, a1 = {0.f, 0.f, 0.f, 0.f};
#pragma unroll
      for (int kc = 0; kc < 4; ++kc) {
        u32x4 b0 = gfrag(W + (h * 32 + lr) * 128 + kc * 32 + lg * 8);
        u32x4 b1 = gfrag(W + (h * 32 + 16 + lr) * 128 + kc * 32 + lg * 8);
        u32x4 a = which ? ax2[kc] : ax1[kc];
        mfma16(a0, a, b0);
        mfma16(a1, a, b1);
      }
      if (!which) {
        float b0 = qb[h * 32 + lr], b1 = qb[h * 32 + 16 + lr];
#pragma unroll
        for (int i = 0; i < 4; ++i) { a0[i] += b0; a1[i] += b1; }
      }
      float s[4];
#pragma unroll
      for (int i = 0; i < 4; ++i) s[i] = a0[i] * a0[i] + a1[i] * a1[i];
#pragma unroll
      for (int m = 1; m < 16; m <<= 1)
#pragma unroll
        for (int i = 0; i < 4; ++i) s[i] += __shfl_xor(s[i], m, 64);
      char* dst = smem + (which ? RB : RA);
#pragma unroll
      for (int i = 0; i < 4; ++i) {
        float r = 1.0f / fmaxf(sqrtf(s[i]), 1e-12f);
        int row = r0 + lg * 4 + i;
        lds_st16(dst, row, (h * 32 + lr) * 2, 256, f2h(a0[i] * r));
        lds_st16(dst, row, (h * 32 + 16 + lr) * 2, 256, f2h(a1[i] * r));
      }
    }
  }
  __syncthreads();  // (3) Q,K complete

  // ---- phase 2: per-wave head wv, fully wave-local after the operand loads ----
  const float sc = scales[wv];  // already includes log2(e)
  u32x4 aq[4], bk[4];
#pragma unroll
  for (int t = 0; t < 4; ++t) {
    aq[t] = ldsfrag(smem + RA, t * 16 + lr, wv * 64 + lg * 16, 256);
    bk[t] = ldsfrag(smem + RB, t * 16 + lr, wv * 64 + lg * 16, 256);
  }
  __syncthreads();  // (4) all Q/K reads done -> A and B both dead:
                    // O may overlay A, P strips may overlay B.

  char* Pbase = smem + RB + wv * 4096;  // wave-private 16x64 f16 strip
  f32x4 o[4][2];
#pragma unroll
  for (int nt = 0; nt < 4; ++nt) {
    // QK^T for q-rows [16nt,16nt+16), all 64 k
    f32x4 att[4];
#pragma unroll
    for (int mt = 0; mt < 4; ++mt) {
      f32x4 z = {0.f, 0.f, 0.f, 0.f};
      mfma16(z, aq[nt], bk[mt]);
      att[mt] = z;
    }
    // softmax; logits*log2e <= sc -> fixed max bound sc (no max reduce); exp2
    float sum[4] = {0.f, 0.f, 0.f, 0.f};
#pragma unroll
    for (int i = 0; i < 4; ++i)
#pragma unroll
      for (int mt = 0; mt < 4; ++mt) {
        float p = exp2f(fmaf(att[mt][i], sc, -sc));
        att[mt][i] = p;
        sum[i] += p;
      }
#pragma unroll
    for (int m = 1; m < 16; m <<= 1)
#pragma unroll
      for (int i = 0; i < 4; ++i) sum[i] += __shfl_xor(sum[i], m, 64);
    // P strip (rows local 0..15) -> wave-private LDS, then PV (wave-local RAW)
#pragma unroll
    for (int i = 0; i < 4; ++i) {
      float rs = 1.0f / sum[i];
      int row = lg * 4 + i;
#pragma unroll
      for (int mt = 0; mt < 4; ++mt)
        lds_st16(Pbase, row, (mt * 16 + lr) * 2, 128, f2h(att[mt][i] * rs));
    }
    u32x4 ap[2];
#pragma unroll
    for (int kc = 0; kc < 2; ++kc)
      ap[kc] = ldsfrag(Pbase, lr, kc * 64 + lg * 16, 128);
#pragma unroll
    for (int ct = 0; ct < 2; ++ct) {
      f32x4 z = {0.f, 0.f, 0.f, 0.f};
#pragma unroll
      for (int kc = 0; kc < 2; ++kc) mfma16(z, ap[kc], bv[ct][kc]);
      o[nt][ct] = z;
    }
  }

  // Hoist phase-3 weight frags (L2) to overlap with O-store + barrier below.
  u32x4 bp[2][4];
#pragma unroll
  for (int ct = 0; ct < 2; ++ct)
#pragma unroll
    for (int kc = 0; kc < 4; ++kc)
      bp[ct][kc] = gfrag(pw + (wv * 32 + ct * 16 + lr) * 128 + kc * 32 + lg * 8);
  float pbv[2] = { pb[wv * 32 + lr], pb[wv * 32 + 16 + lr] };

  // store o (all rows x own head's 32 cols) into A (all aq reads done at barrier 4)
#pragma unroll
  for (int nt = 0; nt < 4; ++nt)
#pragma unroll
    for (int ct = 0; ct < 2; ++ct)
#pragma unroll
      for (int i = 0; i < 4; ++i) {
        int row = nt * 16 + lg * 4 + i;
        lds_st16(smem + RA, row, (wv * 32 + ct * 16 + lr) * 2, 256, f2h(o[nt][ct][i]));
      }
  __syncthreads();  // (5) O complete

  // ---- phase 3 (column-scheme): out[:, 32wv..32wv+32) = O @ pw[own rows]^T + pb ----
  {
    float* ob = out + (size_t)b * 8192;
#pragma unroll
    for (int np = 0; np < 2; ++np) {   // two nt-halves to bound VGPR
      u32x4 af[2][4];
#pragma unroll
      for (int t = 0; t < 2; ++t)
#pragma unroll
        for (int kc = 0; kc < 4; ++kc)
          af[t][kc] = ldsfrag(smem + RA, (np * 2 + t) * 16 + lr, kc * 64 + lg * 16, 256);
#pragma unroll
      for (int t = 0; t < 2; ++t)
#pragma unroll
        for (int ct = 0; ct < 2; ++ct) {
          f32x4 acc = {0.f, 0.f, 0.f, 0.f};
#pragma unroll
          for (int kc = 0; kc < 4; ++kc) mfma16(acc, af[t][kc], bp[ct][kc]);
#pragma unroll
          for (int i = 0; i < 4; ++i) {
            int row = (np * 2 + t) * 16 + lg * 4 + i;
            ob[row * 128 + wv * 32 + ct * 16 + lr] = acc[i] + pbv[ct];
          }
        }
    }
  }
}

extern "C" void kernel_launch(void* const* d_in, const int* in_sizes, int n_in,
                              void* d_out, int out_size, void* d_ws, size_t ws_size,
                              hipStream_t stream) {
  const float* x1 = (const float*)d_in[0];
  const float* x2 = (const float*)d_in[1];
  const float* qw = (const float*)d_in[2];
  const float* qb = (const float*)d_in[3];
  const float* kvw = (const float*)d_in[4];
  const float* vb = (const float*)d_in[5];
  const float* ls = (const float*)d_in[6];
  const float* pw = (const float*)d_in[7];
  const float* pb = (const float*)d_in[8];
  u16* wh = (u16*)d_ws;                           // 65536 f16 = 128 KB
  float* scales = (float*)((char*)d_ws + 131072); // 4 floats

  wca_prep<<<64, 256, 0, stream>>>(qw, kvw, pw, ls, wh, scales);
  wca_kernel<<<NWIN, 256, 0, stream>>>(x1, x2, qb, vb, pb, wh, scales, (float*)d_out);
}